// Round 5
// baseline (83.246 us; speedup 1.0000x reference)
//
#include <hip/hip_runtime.h>
#include <math.h>

// Symmetric Hausdorff, B=8, N=M=4096, D=2, fp32.
// Round 10: R9 showed the MFMA partial is numerically exact (absmax=0) but
// neutral on time -> kernels' inner work is not the marginal cost; the
// ~25us of non-fill time is pipeline structure (3 dispatch gaps + maxred's
// 2-4MB round trip). Collapse to 2 kernels: JC=1 -> each block handles ALL
// 4096 j for its 128 i (staged in 4x 32KB LDS chunks), so min-over-j AND
// max-over-i complete in-block. hk_maxred deleted; partial writes 512 floats.
//   MFMA per 32x32 tile: acc = -2 p.q + |q|^2 via f16 hi/lo splits
//     k0-7:  A = -2*{qxh,qxh,qxl,qxl,qyh,qyh,qyl,qyl}, B = {pxh,pxl,pxh,pxl,
//            pyh,pyl,pyh,pyl};  k8-9: A = {qqh,qql} (lanes 32-63), B = {1,1}.
//   |p|^2 exact fp32, added after min (monotone). zacc hoisted out of the
//   loop so no per-tile acc re-init.
// Fill ~41us is harness-fixed. Pipeline: hk_partial (512) -> hk_final (1).

#define B 8
#define N 4096
#define TPB 256
#define IBLK 128              // i per block = 4 waves x 32
#define NIB (N / IBLK)        // 32 i-blocks
#define JCHUNK 1024           // j staged per LDS pass
#define NCHUNK (N / JCHUNK)   // 4
#define NTC (JCHUNK / 32)     // 32 j-tiles per chunk

typedef _Float16 half8 __attribute__((ext_vector_type(8)));
typedef float f32x16 __attribute__((ext_vector_type(16)));

__global__ __launch_bounds__(TPB) void hk_partial(const float* __restrict__ pred,
                                                  const float* __restrict__ target,
                                                  float* __restrict__ pw) {
    const int ibk = blockIdx.x;
    const int b   = blockIdx.y;
    const int dir = blockIdx.z;

    const float2* __restrict__ P =
        reinterpret_cast<const float2*>(dir == 0 ? pred : target) + (size_t)b * N;
    const float2* __restrict__ Q =
        reinterpret_cast<const float2*>(dir == 0 ? target : pred) + (size_t)b * N;

    // A-operand image for one chunk: 32 tiles x 64 lane-entries x 16 B = 32 KB.
    __shared__ half8 sA[NTC * 64];
    __shared__ float sred[TPB / 64];

    const int lane = threadIdx.x & 63;
    const int wave = threadIdx.x >> 6;
    const int col  = lane & 31;
    const int i    = ibk * IBLK + wave * 32 + col;

    // B-operand fragment (constant across the whole j-loop).
    half8 bf;
    float pp = 0.f;
    if (lane < 32) {
        float2 p = P[i];
        _Float16 xh = (_Float16)p.x;
        _Float16 xl = (_Float16)(p.x - (float)xh);
        _Float16 yh = (_Float16)p.y;
        _Float16 yl = (_Float16)(p.y - (float)yh);
        bf = (half8){xh, xl, xh, xl, yh, yl, yh, yl};
        pp = fmaf(p.x, p.x, p.y * p.y);
    } else {
        const _Float16 one = (_Float16)1.f;
        const _Float16 z   = (_Float16)0.f;
        bf = (half8){one, one, z, z, z, z, z, z};
    }

    const f32x16 zacc = {};   // loop-invariant zero C operand
    float rm[8];
    #pragma unroll
    for (int r = 0; r < 8; ++r) rm[r] = 3.402823466e38f;

    for (int c = 0; c < NCHUNK; ++c) {
        // Stage this chunk's A-image (1024 j-points -> 32 KB).
        for (int s = threadIdx.x; s < JCHUNK; s += TPB) {   // 4 iters
            float2 q = Q[c * JCHUNK + s];
            _Float16 xh = (_Float16)q.x;
            _Float16 xl = (_Float16)(q.x - (float)xh);
            _Float16 yh = (_Float16)q.y;
            _Float16 yl = (_Float16)(q.y - (float)yh);
            float qq = fmaf(q.x, q.x, q.y * q.y);
            _Float16 qqh = (_Float16)qq;
            _Float16 qql = (_Float16)(qq - (float)qqh);
            _Float16 nxh = (_Float16)(-2.f * (float)xh);   // exact scale
            _Float16 nxl = (_Float16)(-2.f * (float)xl);
            _Float16 nyh = (_Float16)(-2.f * (float)yh);
            _Float16 nyl = (_Float16)(-2.f * (float)yl);
            const _Float16 z = (_Float16)0.f;
            int t = s >> 5, m = s & 31;
            sA[t * 64 + m]      = (half8){nxh, nxh, nxl, nxl, nyh, nyh, nyl, nyl};
            sA[t * 64 + 32 + m] = (half8){qqh, qql, z, z, z, z, z, z};
        }
        __syncthreads();

        #pragma unroll 4
        for (int t = 0; t < NTC; ++t) {
            half8 a = sA[t * 64 + lane];
            f32x16 d = __builtin_amdgcn_mfma_f32_32x32x16_f16(a, bf, zacc, 0, 0, 0);
            #pragma unroll
            for (int r = 0; r < 8; ++r)
                rm[r] = fminf(rm[r], fminf(d[2 * r], d[2 * r + 1]));  // v_min3
        }
        __syncthreads();   // before next chunk overwrites sA
    }

    // Finish min over j for this i (rows split across lane-halves).
    float mn = fminf(fminf(fminf(rm[0], rm[1]), fminf(rm[2], rm[3])),
                     fminf(fminf(rm[4], rm[5]), fminf(rm[6], rm[7])));
    mn = fminf(mn, __shfl_xor(mn, 32, 64));

    // Max over the wave's 32 i (lanes >= 32 excluded via -inf).
    float val = (lane < 32) ? mn + pp : -3.402823466e38f;
    #pragma unroll
    for (int off = 16; off > 0; off >>= 1)
        val = fmaxf(val, __shfl_xor(val, off, 64));
    if (lane == 0) sred[wave] = val;
    __syncthreads();
    if (threadIdx.x == 0) {
        float m = sred[0];
        #pragma unroll
        for (int w = 1; w < TPB / 64; ++w) m = fmaxf(m, sred[w]);
        pw[(dir * B + b) * NIB + ibk] = m;   // [dir][b][ibk]
    }
}

// Single block: 512 slots -> 16 (dir,b) maxes -> mean over b of sqrt(max(dirs)).
__global__ __launch_bounds__(64) void hk_final(const float* __restrict__ pw,
                                               float* __restrict__ out) {
    const int t = threadIdx.x;
    __shared__ float h2[2 * B];
    if (t < 2 * B) {
        float mx = pw[t * NIB];
        #pragma unroll
        for (int k = 1; k < NIB; ++k) mx = fmaxf(mx, pw[t * NIB + k]);
        h2[t] = mx;
    }
    __syncthreads();
    if (t == 0) {
        float s = 0.f;
        #pragma unroll
        for (int b = 0; b < B; ++b)
            s += sqrtf(fmaxf(fmaxf(h2[b], h2[B + b]), 0.f));
        out[0] = s * (1.0f / B);
    }
}

extern "C" void kernel_launch(void* const* d_in, const int* in_sizes, int n_in,
                              void* d_out, int out_size, void* d_ws, size_t ws_size,
                              hipStream_t stream) {
    const float* pred   = (const float*)d_in[0];
    const float* target = (const float*)d_in[1];
    float* out = (float*)d_out;
    float* pw  = (float*)d_ws;   // 2*8*32 = 512 floats

    dim3 g1(NIB, B, 2);          // 512 blocks -> 2 blocks/CU, 8 waves/CU
    hk_partial<<<g1, TPB, 0, stream>>>(pred, target, pw);
    hk_final<<<1, 64, 0, stream>>>(pw, out);
}

// Round 6
// 77.838 us; speedup vs baseline: 1.0695x; 1.0695x over previous
//
#include <hip/hip_runtime.h>
#include <hip/hip_bf16.h>
#include <math.h>

// Symmetric Hausdorff, B=8, N=M=4096, D=2, fp32.
// Round 11: REVERT to the best-measured configuration (R5, 77.7us).
// Experiment series (R6-R10) established:
//   - fill 41.7us = harness workspace poison at 84% HBM peak (roofline, fixed)
//   - merging kernels regresses: per-block cross-XCD fences (R7 +6.5us) or
//     serialized stage/compute at low occupancy (R10 +4us) cost more than
//     the saved dispatch gap
//   - halving pw traffic (R8) and MFMA inner loop (R9) are neutral: the
//     non-fill remainder is dispatch-floor + hk_partial's fp32 issue floor
//     (~2.5 inst/pair/dir; no fp32 MFMA on CDNA4).
// Pipeline: hk_partial (1024) -> hk_maxred (256) -> hk_final (1).

#define B 8
#define N 4096
#define TPB 256
#define IB 8              // i-points per thread
#define JC 32             // j-chunks per (b,dir)
#define JTILE (N / JC)    // 128 j-points per block
#define ITILES (N / TPB)  // 16 i-tiles for the reduce stage

__global__ __launch_bounds__(TPB) void hk_partial(const float* __restrict__ pred,
                                                  const float* __restrict__ target,
                                                  float* __restrict__ pw) {
    const int bx  = blockIdx.x;        // 0..63: [ib: 0..1] x [jc: 0..31]
    const int ib  = bx & 1;
    const int jc  = bx >> 1;
    const int b   = blockIdx.y;
    const int dir = blockIdx.z;

    const float2* __restrict__ P =
        reinterpret_cast<const float2*>(dir == 0 ? pred : target) + (size_t)b * N;
    const float*  __restrict__ Qf =
        (dir == 0 ? target : pred) + (size_t)b * N * 2 + (size_t)jc * JTILE * 2;

    // Stage this block's 128 j-points as 64 float4 (2 points each). 1 KB LDS.
    __shared__ float4 sQ[JTILE / 2];
    if (threadIdx.x < JTILE / 2)
        sQ[threadIdx.x] = reinterpret_cast<const float4*>(Qf)[threadIdx.x];
    __syncthreads();

    // This thread's IB source points (strided by TPB so pw stores coalesce).
    float m2x[IB], m2y[IB], pp[IB], mn[IB];
    const int i0 = ib * (TPB * IB) + threadIdx.x;
    #pragma unroll
    for (int k = 0; k < IB; ++k) {
        float2 p = P[i0 + k * TPB];
        m2x[k] = -2.f * p.x;
        m2y[k] = -2.f * p.y;
        pp[k]  = fmaf(p.x, p.x, p.y * p.y);
        mn[k]  = 3.402823466e38f;
    }

    // min_j(|q|^2 - 2 p.q): per iter 1 broadcast b128 (2 points) + 44 VALU.
    #pragma unroll 4
    for (int j = 0; j < JTILE / 2; ++j) {
        float4 q = sQ[j];
        float qqa = fmaf(q.x, q.x, q.y * q.y);
        float qqb = fmaf(q.z, q.z, q.w * q.w);
        #pragma unroll
        for (int k = 0; k < IB; ++k) {
            float ta = fmaf(m2x[k], q.x, fmaf(m2y[k], q.y, qqa));
            float tb = fmaf(m2x[k], q.z, fmaf(m2y[k], q.w, qqb));
            mn[k] = fminf(mn[k], fminf(ta, tb));   // v_min3_f32
        }
    }

    // Partial min for this j-chunk, |p|^2 restored. Layout: [dir][b][jc][i].
    float* dst = pw + (size_t)((dir * B + b) * JC + jc) * N;
    #pragma unroll
    for (int k = 0; k < IB; ++k)
        dst[i0 + k * TPB] = mn[k] + pp[k];
}

// One block per (i-tile, b, dir): min over 32 jc (coalesced), block max-reduce,
// write to a private slot — no atomics, no init required.
__global__ __launch_bounds__(TPB) void hk_maxred(const float* __restrict__ pw,
                                                 float* __restrict__ pw2) {
    const int tile = blockIdx.x;
    const int b    = blockIdx.y;
    const int dir  = blockIdx.z;
    const int t    = threadIdx.x;

    const float* base = pw + (size_t)((dir * B + b) * JC) * N + tile * TPB + t;
    float mnv = base[0];
    #pragma unroll
    for (int jc = 1; jc < JC; ++jc) mnv = fminf(mnv, base[(size_t)jc * N]);

    float mx = mnv;
    #pragma unroll
    for (int off = 32; off > 0; off >>= 1)
        mx = fmaxf(mx, __shfl_down(mx, off, 64));

    __shared__ float sred[TPB / 64];
    if ((t & 63) == 0) sred[t >> 6] = mx;
    __syncthreads();
    if (t == 0) {
        float bm = sred[0];
        #pragma unroll
        for (int w = 1; w < TPB / 64; ++w) bm = fmaxf(bm, sred[w]);
        pw2[(dir * B + b) * ITILES + tile] = bm;   // [dir][b][tile]
    }
}

// Single block: 256 slots -> 16 (dir,b) maxes -> mean over b of sqrt(max(dirs)).
__global__ __launch_bounds__(64) void hk_final(const float* __restrict__ pw2,
                                               float* __restrict__ out) {
    const int t = threadIdx.x;
    __shared__ float h2[2 * B];
    if (t < 2 * B) {
        float mx = pw2[t * ITILES];
        #pragma unroll
        for (int k = 1; k < ITILES; ++k) mx = fmaxf(mx, pw2[t * ITILES + k]);
        h2[t] = mx;
    }
    __syncthreads();
    if (t == 0) {
        float s = 0.f;
        #pragma unroll
        for (int b = 0; b < B; ++b)
            s += sqrtf(fmaxf(fmaxf(h2[b], h2[B + b]), 0.f));
        out[0] = s * (1.0f / B);
    }
}

extern "C" void kernel_launch(void* const* d_in, const int* in_sizes, int n_in,
                              void* d_out, int out_size, void* d_ws, size_t ws_size,
                              hipStream_t stream) {
    const float* pred   = (const float*)d_in[0];
    const float* target = (const float*)d_in[1];
    float* out = (float*)d_out;
    float* pw  = (float*)d_ws;                       // 2*8*32*4096 floats = 8 MB
    float* pw2 = (float*)((char*)d_ws + (size_t)2 * B * JC * N * sizeof(float)); // 256 floats

    dim3 g1(64, B, 2);           // 1024 blocks -> 4 blocks/CU, 16 waves/CU
    hk_partial<<<g1, TPB, 0, stream>>>(pred, target, pw);
    dim3 g2(ITILES, B, 2);       // 256 blocks
    hk_maxred<<<g2, TPB, 0, stream>>>(pw, pw2);
    hk_final<<<1, 64, 0, stream>>>(pw2, out);
}